// Round 3
// baseline (21763.733 us; speedup 1.0000x reference)
//
#include <hip/hip_runtime.h>
#include <hip/hip_bf16.h>
#include <hip/hip_fp16.h>

#define N_NODES 131072
#define N_EDGES 2097152
#define BSZ     4096
#define NREL    5
#define NBASIS  4

typedef unsigned int uint;
typedef unsigned short ushort;
typedef _Float16 v2h __attribute__((ext_vector_type(2)));
typedef __attribute__((ext_vector_type(8))) short bf16x8;
typedef __attribute__((ext_vector_type(4))) float f32x4;

__device__ __forceinline__ float bflo(uint u){ union{uint i;float f;}x; x.i = u<<16; return x.f; }
__device__ __forceinline__ float bf2f(ushort u){ return bflo((uint)u); }
__device__ __forceinline__ ushort f2bf(float f){
  union{float f;uint i;}x; x.f=f;
  uint r = (x.i + 0x7fffu + ((x.i>>16)&1u)) >> 16;
  return (ushort)r;
}
__device__ __forceinline__ float sigm(float x){ return 1.0f/(1.0f+__expf(-x)); }
__device__ __forceinline__ float tanh_fast(float x){
  x = fminf(fmaxf(x,-15.f),15.f);
  float e = __expf(2.0f*x);
  return (e-1.0f)/(e+1.0f);
}
__device__ __forceinline__ float dot2h(uint a, uint b, float c){
#if __has_builtin(__builtin_amdgcn_fdot2)
  return __builtin_amdgcn_fdot2(__builtin_bit_cast(v2h,a), __builtin_bit_cast(v2h,b), c, false);
#else
  v2h ah = __builtin_bit_cast(v2h,a), bh = __builtin_bit_cast(v2h,b);
  return c + (float)ah.x*(float)bh.x + (float)ah.y*(float)bh.y;
#endif
}

__global__ void k_cvt_half(const float* __restrict__ in, __half* __restrict__ out, int n){
  int i = blockIdx.x*256 + threadIdx.x;
  if (i < n) out[i] = __float2half(in[i]);
}
__global__ void k_cvt_bf(const float* __restrict__ in, ushort* __restrict__ out, int n){
  int i = blockIdx.x*256 + threadIdx.x;
  if (i < n) out[i] = f2bf(in[i]);
}

__global__ void k_count(const int* __restrict__ ei, const int* __restrict__ et, int* __restrict__ cnt){
  int e = blockIdx.x*256 + threadIdx.x;
  if (e < N_EDGES){
    int d = ei[N_EDGES + e];
    int r = et[e];
    atomicAdd(&cnt[d*NREL + r], 1);
  }
}
__global__ void k_inv(float* __restrict__ buf){
  int i = blockIdx.x*256 + threadIdx.x;
  if (i < N_NODES*NREL){
    int c = ((int*)buf)[i];
    buf[i] = (c > 0) ? (1.0f/(float)c) : 1.0f;
  }
}

// hb[n][j][b] = sum_i h[n,i]*basis[b,i,j], packed 4 bf16 per (n,j)
__global__ void k_hb(const float* __restrict__ x, const ushort* __restrict__ states, int l,
                     const float* __restrict__ basis_l, uint2* __restrict__ hb){
  __shared__ float bs[NBASIS*32*32];
  __shared__ float hs[256];
  int tid = threadIdx.x;
  #pragma unroll
  for (int r = 0; r < 16; r++){ int idx = r*256 + tid; bs[idx] = basis_l[idx]; }
  int nbase = blockIdx.x*8;
  if (l == 0){
    hs[tid] = x[nbase*32 + tid];
  } else {
    int n = nbase + (tid >> 5), i = tid & 31;
    hs[tid] = bf2f(states[n*128 + (l-1)*32 + i]);
  }
  __syncthreads();
  int nl = tid >> 5, j = tid & 31;
  float a0=0.f,a1=0.f,a2=0.f,a3=0.f;
  #pragma unroll
  for (int i = 0; i < 32; i++){
    float hv = hs[nl*32 + i];
    a0 += hv*bs[0*1024 + i*32 + j];
    a1 += hv*bs[1*1024 + i*32 + j];
    a2 += hv*bs[2*1024 + i*32 + j];
    a3 += hv*bs[3*1024 + i*32 + j];
  }
  uint2 o;
  o.x = (uint)f2bf(a0) | ((uint)f2bf(a1) << 16);
  o.y = (uint)f2bf(a2) | ((uint)f2bf(a3) << 16);
  hb[(nbase + nl)*32 + j] = o;
}

__global__ void k_edge(const int* __restrict__ ei, const int* __restrict__ et,
                       const float* __restrict__ comp_l, const float* __restrict__ inv,
                       const uint2* __restrict__ hb, float* __restrict__ agg){
  __shared__ float cl[NREL*NBASIS];
  int tid = threadIdx.x;
  if (tid < NREL*NBASIS) cl[tid] = comp_l[tid];
  __syncthreads();
  int e = blockIdx.x*8 + (tid >> 5);
  int j = tid & 31;
  int src = ei[e];
  int dst = ei[N_EDGES + e];
  int r = et[e];
  float nrm = inv[dst*NREL + r];
  uint2 v = hb[src*32 + j];
  float m = nrm*(cl[r*4+0]*bflo(v.x)       + cl[r*4+1]*bflo(v.x >> 16)
               + cl[r*4+2]*bflo(v.y)       + cl[r*4+3]*bflo(v.y >> 16));
  atomicAdd(&agg[dst*32 + j], m);
}

__global__ void k_combine(const float* __restrict__ agg, const float* __restrict__ x,
                          ushort* __restrict__ states, int l,
                          const float* __restrict__ root_l, const float* __restrict__ bias_l){
  __shared__ float rt[1024];
  __shared__ float hs[256];
  int tid = threadIdx.x;
  #pragma unroll
  for (int r = 0; r < 4; r++) rt[r*256 + tid] = root_l[r*256 + tid];
  int nbase = blockIdx.x*8;
  if (l == 0){
    hs[tid] = x[nbase*32 + tid];
  } else {
    int n = nbase + (tid >> 5), i = tid & 31;
    hs[tid] = bf2f(states[n*128 + (l-1)*32 + i]);
  }
  __syncthreads();
  int nl = tid >> 5, j = tid & 31;
  int n = nbase + nl;
  float acc = agg[n*32 + j] + bias_l[j];
  #pragma unroll
  for (int i = 0; i < 32; i++) acc += hs[nl*32 + i] * rt[i*32 + j];
  states[n*128 + l*32 + j] = f2bf(tanh_fast(acc));
}

__global__ void k_gather(const ushort* __restrict__ states, const int* __restrict__ uidx,
                         const int* __restrict__ vidx, ushort* __restrict__ z){
  int b = blockIdx.x;
  int k = threadIdx.x;                       // 256
  int node = (k < 128) ? uidx[b] : vidx[b];
  z[b*256 + k] = states[node*128 + (k & 127)];
}

__global__ void k_xgemm(const ushort* __restrict__ A, const ushort* __restrict__ W,
                        const float* __restrict__ bih, const float* __restrict__ bhh,
                        float* __restrict__ xg){
  int gw = blockIdx.x*4 + (threadIdx.x >> 6);
  int lane = threadIdx.x & 63;
  int t0 = (gw >> 6)*16;
  int j0 = (gw & 63)*16;
  int m = lane & 15, q = lane >> 4;
  const ushort* ap = A + (t0 + m)*256 + q*8;
  const ushort* bp = W + (j0 + m)*256 + q*8;
  f32x4 acc = {0.f,0.f,0.f,0.f};
  #pragma unroll
  for (int kk = 0; kk < 8; kk++){
    bf16x8 a = *(const bf16x8*)(ap + kk*32);
    bf16x8 b = *(const bf16x8*)(bp + kk*32);
    acc = __builtin_amdgcn_mfma_f32_16x16x32_bf16(a, b, acc, 0, 0, 0);
  }
  int j = j0 + m;
  float bias = bih[j] + bhh[j];
  #pragma unroll
  for (int r = 0; r < 4; r++){
    int t = t0 + q*4 + r;                    // C: col=lane&15, row=quad*4+reg (m89)
    xg[t*1024 + j] = acc[r] + bias;
  }
}

// ---- 4-WG cooperative LSTM scan ----
// Workers at blockIdx {0,8,16,24} (same XCD under common mappings; correct anywhere).
// WG g owns units u in [g*64,(g+1)*64): thread t -> gate q=t>>6, row q*256+g*64+(t&63).
// All 128 weight uints per thread in named uint4 registers (no arrays -> no spill).
// Cross-WG h exchange: hglob (fp16, double-buffered by parity) + per-WG seq words
// (release/acquire, agent scope). seq zeroed by memset before each launch.
#define REP32(M) M(0)M(1)M(2)M(3)M(4)M(5)M(6)M(7)M(8)M(9)M(10)M(11)M(12)M(13)M(14)M(15)M(16)M(17)M(18)M(19)M(20)M(21)M(22)M(23)M(24)M(25)M(26)M(27)M(28)M(29)M(30)M(31)

__launch_bounds__(256, 1)
__global__ void k_scan4(const float* __restrict__ xg, const __half* __restrict__ whh,
                        ushort* __restrict__ outh, uint* seq, uint* hglob){
  int b = blockIdx.x;
  if (b & 7) return;
  int wg = b >> 3;
  if (wg >= 4) return;
  __shared__ uint hlds[128];                 // 256 fp16: h_{t-1}
  __shared__ float gx[256];                  // gate exchange
  int t = threadIdx.x;
  int q = t >> 6, uo = t & 63;
  int row = q*256 + wg*64 + uo;
  const uint4* wp = (const uint4*)(whh + (size_t)row*256);
#define W_DECL(i) uint4 W##i = wp[i];
  REP32(W_DECL)
  const uint4* hl = (const uint4*)hlds;
  if (t < 128) hlds[t] = 0u;
  float c = 0.f;
  float px = xg[row];
  __syncthreads();
  for (int step = 0; step < 4096; step++){
    int par = step & 1;
    float acc0 = px, acc1 = 0.f, acc2 = 0.f, acc3 = 0.f;
    int nstep = (step < 4095) ? step + 1 : step;
    px = xg[(size_t)nstep*1024 + row];
#define W_DOT(i) { uint4 h4 = hl[i]; \
    acc0 = dot2h(W##i.x, h4.x, acc0); acc1 = dot2h(W##i.y, h4.y, acc1); \
    acc2 = dot2h(W##i.z, h4.z, acc2); acc3 = dot2h(W##i.w, h4.w, acc3); }
    REP32(W_DOT)
    gx[t] = (acc0 + acc1) + (acc2 + acc3);
    __syncthreads();
    if (t < 64){
      float iv = sigm(gx[t]);
      float fv = sigm(gx[64 + t]);
      float gv = tanh_fast(gx[128 + t]);
      float ov = sigm(gx[192 + t]);
      c = fv*c + iv*gv;
      float hv = ov*tanh_fast(c);
      ((__half*)hglob)[par*256 + wg*64 + t] = __float2half(hv);
      outh[(size_t)step*256 + wg*64 + t] = f2bf(hv);
      if (t == 0)
        __hip_atomic_store(&seq[wg*64], (uint)(step+1), __ATOMIC_RELEASE, __HIP_MEMORY_SCOPE_AGENT);
    }
    if (t < 128){
      const uint* sp = &seq[(t >> 5)*64];    // producer of my uint = t/32
      while (__hip_atomic_load(sp, __ATOMIC_ACQUIRE, __HIP_MEMORY_SCOPE_AGENT) <= (uint)step) {}
      hlds[t] = hglob[par*128 + t];
    }
    __syncthreads();
  }
}

__global__ void k_head1(const ushort* __restrict__ h, const float* __restrict__ w,
                        const float* __restrict__ b, float* __restrict__ out){
  __shared__ float s[256];
  int t = blockIdx.x, j = threadIdx.x;       // 128 threads
  s[j]       = bf2f(h[t*256 + j]);
  s[j + 128] = bf2f(h[t*256 + 128 + j]);
  __syncthreads();
  float acc = b[j];
  const float4* wr4 = (const float4*)(w + j*256);
  #pragma unroll
  for (int k4 = 0; k4 < 64; k4++){
    float4 v = wr4[k4];
    int k = k4*4;
    acc += s[k+0]*v.x + s[k+1]*v.y + s[k+2]*v.z + s[k+3]*v.w;
  }
  out[t*128 + j] = fmaxf(acc, 0.f);
}
__global__ void k_head2(const float* __restrict__ hm, const float* __restrict__ w,
                        const float* __restrict__ b, float* __restrict__ out){
  int t = blockIdx.x*256 + threadIdx.x;
  if (t < BSZ){
    float acc = b[0];
    #pragma unroll
    for (int k = 0; k < 128; k++) acc += hm[t*128 + k]*w[k];
    out[t] = acc;
  }
}

extern "C" void kernel_launch(void* const* d_in, const int* in_sizes, int n_in,
                              void* d_out, int out_size, void* d_ws, size_t ws_size,
                              hipStream_t stream){
  const float* x     = (const float*)d_in[0];
  const int*   ei    = (const int*)d_in[1];
  const int*   et    = (const int*)d_in[2];
  const int*   uidx  = (const int*)d_in[3];
  const int*   vidx  = (const int*)d_in[4];
  const float* basis = (const float*)d_in[5];
  const float* comp  = (const float*)d_in[6];
  const float* root  = (const float*)d_in[7];
  const float* cbias = (const float*)d_in[8];
  const float* w_ih  = (const float*)d_in[9];
  const float* w_hh  = (const float*)d_in[10];
  const float* b_ih  = (const float*)d_in[11];
  const float* b_hh  = (const float*)d_in[12];
  const float* lin1w = (const float*)d_in[13];
  const float* lin1b = (const float*)d_in[14];
  const float* lin2w = (const float*)d_in[15];
  const float* lin2b = (const float*)d_in[16];

  char* ws = (char*)d_ws;
  __half* whh16  = (__half*)(ws + 0);                 // 1 MB
  ushort* wihbf  = (ushort*)(ws + 1048576);           // 1 MB
  float*  inv    = (float*) (ws + 2097152);           // 2.5 MB
  ushort* states = (ushort*)(ws + 4718592);           // 32 MB
  char*   scr    = ws + 38273024;                     // scratch union
  uint2*  hb     = (uint2*)(scr);                     // GNN: 32 MB
  float*  agg    = (float*)(scr + 33554432);          // GNN: 16 MB
  ushort* z      = (ushort*)(scr + 0);                // LSTM phase aliases
  ushort* out1   = (ushort*)(scr + 2097152);
  ushort* out2   = (ushort*)(scr + 4194304);
  float*  hmid   = (float*) (scr + 6291456);
  float*  xg     = (float*) (scr + 8388608);          // 16 MB, ends scr+25165824
  uint*   seq    = (uint*)  (scr + 25165824);         // 1 KB (4 words, 256B apart)
  uint*   hglob  = (uint*)  (scr + 25166848);         // 1 KB (2 x 256 fp16)

  k_cvt_half<<<2048, 256, 0, stream>>>(w_hh, whh16, 2*1024*256);
  k_cvt_bf  <<<2048, 256, 0, stream>>>(w_ih, wihbf, 2*1024*256);
  hipMemsetAsync(inv, 0, (size_t)N_NODES*NREL*4, stream);
  k_count<<<N_EDGES/256, 256, 0, stream>>>(ei, et, (int*)inv);
  k_inv<<<(N_NODES*NREL)/256, 256, 0, stream>>>(inv);

  for (int l = 0; l < 4; l++){
    k_hb<<<N_NODES/8, 256, 0, stream>>>(x, states, l, basis + l*NBASIS*1024, hb);
    hipMemsetAsync(agg, 0, (size_t)N_NODES*32*4, stream);
    k_edge<<<N_EDGES/8, 256, 0, stream>>>(ei, et, comp + l*NREL*NBASIS, inv, hb, agg);
    k_combine<<<N_NODES/8, 256, 0, stream>>>(agg, x, states, l, root + l*1024, cbias + l*32);
  }

  k_gather<<<BSZ, 256, 0, stream>>>(states, uidx, vidx, z);
  k_xgemm<<<4096, 256, 0, stream>>>(z,    wihbf,          b_ih,        b_hh,        xg);
  hipMemsetAsync(seq, 0, 1024, stream);
  k_scan4<<<25, 256, 0, stream>>>(xg, whh16,          out1, seq, hglob);
  k_xgemm<<<4096, 256, 0, stream>>>(out1, wihbf + 262144, b_ih + 1024, b_hh + 1024, xg);
  hipMemsetAsync(seq, 0, 1024, stream);
  k_scan4<<<25, 256, 0, stream>>>(xg, whh16 + 262144, out2, seq, hglob);
  k_head1<<<BSZ, 128, 0, stream>>>(out2, lin1w, lin1b, hmid);
  k_head2<<<BSZ/256, 256, 0, stream>>>(hmid, lin2w, lin2b, (float*)d_out);
}

// Round 4
// 19786.278 us; speedup vs baseline: 1.0999x; 1.0999x over previous
//
#include <hip/hip_runtime.h>
#include <hip/hip_bf16.h>
#include <hip/hip_fp16.h>

#define N_NODES 131072
#define N_EDGES 2097152
#define BSZ     4096
#define NREL    5
#define NBASIS  4

typedef unsigned int uint;
typedef unsigned short ushort;
typedef _Float16 v2h __attribute__((ext_vector_type(2)));
typedef __attribute__((ext_vector_type(8))) short bf16x8;
typedef __attribute__((ext_vector_type(4))) float f32x4;

__device__ __forceinline__ float bflo(uint u){ union{uint i;float f;}x; x.i = u<<16; return x.f; }
__device__ __forceinline__ float bf2f(ushort u){ return bflo((uint)u); }
__device__ __forceinline__ ushort f2bf(float f){
  union{float f;uint i;}x; x.f=f;
  uint r = (x.i + 0x7fffu + ((x.i>>16)&1u)) >> 16;
  return (ushort)r;
}
__device__ __forceinline__ float sigm(float x){ return 1.0f/(1.0f+__expf(-x)); }
__device__ __forceinline__ float tanh_fast(float x){
  x = fminf(fmaxf(x,-15.f),15.f);
  float e = __expf(2.0f*x);
  return (e-1.0f)/(e+1.0f);
}
__device__ __forceinline__ float dot2h(uint a, uint b, float c){
#if __has_builtin(__builtin_amdgcn_fdot2)
  return __builtin_amdgcn_fdot2(__builtin_bit_cast(v2h,a), __builtin_bit_cast(v2h,b), c, false);
#else
  v2h ah = __builtin_bit_cast(v2h,a), bh = __builtin_bit_cast(v2h,b);
  return c + (float)ah.x*(float)bh.x + (float)ah.y*(float)bh.y;
#endif
}

__global__ void k_cvt_half(const float* __restrict__ in, __half* __restrict__ out, int n){
  int i = blockIdx.x*256 + threadIdx.x;
  if (i < n) out[i] = __float2half(in[i]);
}
__global__ void k_cvt_bf(const float* __restrict__ in, ushort* __restrict__ out, int n){
  int i = blockIdx.x*256 + threadIdx.x;
  if (i < n) out[i] = f2bf(in[i]);
}

__global__ void k_count(const int* __restrict__ ei, const int* __restrict__ et, int* __restrict__ cnt){
  int e = blockIdx.x*256 + threadIdx.x;
  if (e < N_EDGES){
    int d = ei[N_EDGES + e];
    int r = et[e];
    atomicAdd(&cnt[d*NREL + r], 1);
  }
}
__global__ void k_inv(float* __restrict__ buf){
  int i = blockIdx.x*256 + threadIdx.x;
  if (i < N_NODES*NREL){
    int c = ((int*)buf)[i];
    buf[i] = (c > 0) ? (1.0f/(float)c) : 1.0f;
  }
}

// hb[n][j][b] = sum_i h[n,i]*basis[b,i,j], packed 4 bf16 per (n,j)
__global__ void k_hb(const float* __restrict__ x, const ushort* __restrict__ states, int l,
                     const float* __restrict__ basis_l, uint2* __restrict__ hb){
  __shared__ float bs[NBASIS*32*32];
  __shared__ float hs[256];
  int tid = threadIdx.x;
  #pragma unroll
  for (int r = 0; r < 16; r++){ int idx = r*256 + tid; bs[idx] = basis_l[idx]; }
  int nbase = blockIdx.x*8;
  if (l == 0){
    hs[tid] = x[nbase*32 + tid];
  } else {
    int n = nbase + (tid >> 5), i = tid & 31;
    hs[tid] = bf2f(states[n*128 + (l-1)*32 + i]);
  }
  __syncthreads();
  int nl = tid >> 5, j = tid & 31;
  float a0=0.f,a1=0.f,a2=0.f,a3=0.f;
  #pragma unroll
  for (int i = 0; i < 32; i++){
    float hv = hs[nl*32 + i];
    a0 += hv*bs[0*1024 + i*32 + j];
    a1 += hv*bs[1*1024 + i*32 + j];
    a2 += hv*bs[2*1024 + i*32 + j];
    a3 += hv*bs[3*1024 + i*32 + j];
  }
  uint2 o;
  o.x = (uint)f2bf(a0) | ((uint)f2bf(a1) << 16);
  o.y = (uint)f2bf(a2) | ((uint)f2bf(a3) << 16);
  hb[(nbase + nl)*32 + j] = o;
}

__global__ void k_edge(const int* __restrict__ ei, const int* __restrict__ et,
                       const float* __restrict__ comp_l, const float* __restrict__ inv,
                       const uint2* __restrict__ hb, float* __restrict__ agg){
  __shared__ float cl[NREL*NBASIS];
  int tid = threadIdx.x;
  if (tid < NREL*NBASIS) cl[tid] = comp_l[tid];
  __syncthreads();
  int e = blockIdx.x*8 + (tid >> 5);
  int j = tid & 31;
  int src = ei[e];
  int dst = ei[N_EDGES + e];
  int r = et[e];
  float nrm = inv[dst*NREL + r];
  uint2 v = hb[src*32 + j];
  float m = nrm*(cl[r*4+0]*bflo(v.x)       + cl[r*4+1]*bflo(v.x >> 16)
               + cl[r*4+2]*bflo(v.y)       + cl[r*4+3]*bflo(v.y >> 16));
  atomicAdd(&agg[dst*32 + j], m);
}

__global__ void k_combine(const float* __restrict__ agg, const float* __restrict__ x,
                          ushort* __restrict__ states, int l,
                          const float* __restrict__ root_l, const float* __restrict__ bias_l){
  __shared__ float rt[1024];
  __shared__ float hs[256];
  int tid = threadIdx.x;
  #pragma unroll
  for (int r = 0; r < 4; r++) rt[r*256 + tid] = root_l[r*256 + tid];
  int nbase = blockIdx.x*8;
  if (l == 0){
    hs[tid] = x[nbase*32 + tid];
  } else {
    int n = nbase + (tid >> 5), i = tid & 31;
    hs[tid] = bf2f(states[n*128 + (l-1)*32 + i]);
  }
  __syncthreads();
  int nl = tid >> 5, j = tid & 31;
  int n = nbase + nl;
  float acc = agg[n*32 + j] + bias_l[j];
  #pragma unroll
  for (int i = 0; i < 32; i++) acc += hs[nl*32 + i] * rt[i*32 + j];
  states[n*128 + l*32 + j] = f2bf(tanh_fast(acc));
}

__global__ void k_gather(const ushort* __restrict__ states, const int* __restrict__ uidx,
                         const int* __restrict__ vidx, ushort* __restrict__ z){
  int b = blockIdx.x;
  int k = threadIdx.x;                       // 256
  int node = (k < 128) ? uidx[b] : vidx[b];
  z[b*256 + k] = states[node*128 + (k & 127)];
}

__global__ void k_xgemm(const ushort* __restrict__ A, const ushort* __restrict__ W,
                        const float* __restrict__ bih, const float* __restrict__ bhh,
                        float* __restrict__ xg){
  int gw = blockIdx.x*4 + (threadIdx.x >> 6);
  int lane = threadIdx.x & 63;
  int t0 = (gw >> 6)*16;
  int j0 = (gw & 63)*16;
  int m = lane & 15, q = lane >> 4;
  const ushort* ap = A + (t0 + m)*256 + q*8;
  const ushort* bp = W + (j0 + m)*256 + q*8;
  f32x4 acc = {0.f,0.f,0.f,0.f};
  #pragma unroll
  for (int kk = 0; kk < 8; kk++){
    bf16x8 a = *(const bf16x8*)(ap + kk*32);
    bf16x8 b = *(const bf16x8*)(bp + kk*32);
    acc = __builtin_amdgcn_mfma_f32_16x16x32_bf16(a, b, acc, 0, 0, 0);
  }
  int j = j0 + m;
  float bias = bih[j] + bhh[j];
  #pragma unroll
  for (int r = 0; r < 4; r++){
    int t = t0 + q*4 + r;                    // C: col=lane&15, row=quad*4+reg (m89)
    xg[t*1024 + j] = acc[r] + bias;
  }
}

// ---- 4-WG cooperative LSTM scan, quad-split dot + DPP reduce ----
// WG g owns units u in [g*64,(g+1)*64). Thread: wave w=t>>6, lane l; quad qd=l>>2,
// sub s=l&3. Unit u = g*64+w*16+qd; thread computes k-quarter [64s,64s+64) of all
// 4 gate rows {q*256+u}. Partials reduced across s via DPP quad_perm butterflies.
// W_hh held in 128 pinned VGPR uints/thread (asm pin prevents sinking/remat).
// LDS h: double-buffered, 4 quarters of 32 uints padded to 36 (bank-conflict-free
// b128 reads). Cross-WG exchange: hglob fp16 (parity buffers) + seq release/acquire.
#define REP8J(M,q) M(q,0) M(q,1) M(q,2) M(q,3) M(q,4) M(q,5) M(q,6) M(q,7)
#define REPQ(M) REP8J(M,0) REP8J(M,1) REP8J(M,2) REP8J(M,3)
#define WDECL(q,j) uint4 W##q##_##j = wp##q[j];
#define WPIN(q,j)  asm volatile("" : "+v"(W##q##_##j.x), "+v"(W##q##_##j.y), \
                                     "+v"(W##q##_##j.z), "+v"(W##q##_##j.w));
#define DOTJ(j) { uint4 H = hp[j]; \
  a0 = dot2h(W0_##j.x, H.x, a0); b0 = dot2h(W0_##j.y, H.y, b0); \
  a0 = dot2h(W0_##j.z, H.z, a0); b0 = dot2h(W0_##j.w, H.w, b0); \
  a1 = dot2h(W1_##j.x, H.x, a1); b1 = dot2h(W1_##j.y, H.y, b1); \
  a1 = dot2h(W1_##j.z, H.z, a1); b1 = dot2h(W1_##j.w, H.w, b1); \
  a2 = dot2h(W2_##j.x, H.x, a2); b2 = dot2h(W2_##j.y, H.y, b2); \
  a2 = dot2h(W2_##j.z, H.z, a2); b2 = dot2h(W2_##j.w, H.w, b2); \
  a3 = dot2h(W3_##j.x, H.x, a3); b3 = dot2h(W3_##j.y, H.y, b3); \
  a3 = dot2h(W3_##j.z, H.z, a3); b3 = dot2h(W3_##j.w, H.w, b3); }
#define BFLY(r) { \
  float _t = __int_as_float(__builtin_amdgcn_update_dpp(0, __float_as_int(r), 0xB1, 0xF, 0xF, true)); \
  r += _t; \
  _t = __int_as_float(__builtin_amdgcn_update_dpp(0, __float_as_int(r), 0x4E, 0xF, 0xF, true)); \
  r += _t; }

__launch_bounds__(256, 1)
__global__ void k_scan4(const float* __restrict__ xg, const __half* __restrict__ whh,
                        ushort* __restrict__ outh, uint* seq, uint* hglob){
  int b = blockIdx.x;
  if (b & 7) return;
  int g = b >> 3;
  if (g >= 4) return;
  __shared__ uint hq[2][4*36];               // 2 bufs x 4 quarters x 36 uints (pad)
  int t = threadIdx.x;
  int w = t >> 6, lane = t & 63, qd = lane >> 2, s = lane & 3;
  int u = g*64 + w*16 + qd;
  const uint4* wp0 = (const uint4*)(whh + ((size_t)(u      ))*256 + s*64);
  const uint4* wp1 = (const uint4*)(whh + ((size_t)(u + 256))*256 + s*64);
  const uint4* wp2 = (const uint4*)(whh + ((size_t)(u + 512))*256 + s*64);
  const uint4* wp3 = (const uint4*)(whh + ((size_t)(u + 768))*256 + s*64);
  REPQ(WDECL)
  REPQ(WPIN)
  if (t < 144){ hq[0][t] = 0u; }
  float c = 0.f;
  float px = xg[s*256 + u];
  __syncthreads();
  for (int step = 0; step < 4096; step++){
    int rb = step & 1, wb = rb ^ 1;
    const uint4* hp = (const uint4*)&hq[rb][s*36];
    float a0=0.f,a1=0.f,a2=0.f,a3=0.f,b0=0.f,b1=0.f,b2=0.f,b3=0.f;
    int nstep = (step < 4095) ? step + 1 : step;
    float npx = xg[(size_t)nstep*1024 + s*256 + u];
    DOTJ(0) DOTJ(1) DOTJ(2) DOTJ(3) DOTJ(4) DOTJ(5) DOTJ(6) DOTJ(7)
    float r0 = a0 + b0, r1 = a1 + b1, r2 = a2 + b2, r3 = a3 + b3;
    r0 += (s == 0) ? px : 0.f;
    r1 += (s == 1) ? px : 0.f;
    r2 += (s == 2) ? px : 0.f;
    r3 += (s == 3) ? px : 0.f;
    BFLY(r0) BFLY(r1) BFLY(r2) BFLY(r3)
    float iv = sigm(r0), fv = sigm(r1), gv = tanh_fast(r2), ov = sigm(r3);
    c = fv*c + iv*gv;
    float hv = ov*tanh_fast(c);
    px = npx;
    if (s == 0){
      __half hh = __float2half(hv);
      ((__half*)&hq[wb][g*36])[w*16 + qd] = hh;   // own quarter, write buffer
      ((__half*)hglob)[rb*256 + u] = hh;          // export
      outh[(size_t)step*256 + u] = f2bf(hv);
    }
    __syncthreads();                              // drains vmcnt: exports visible
    if (t == 0)
      __hip_atomic_store(&seq[g*64], (uint)(step+1), __ATOMIC_RELEASE, __HIP_MEMORY_SCOPE_AGENT);
    if (t < 96){
      int o = t >> 5, idx = t & 31;
      int gg = o + (o >= g);
      const uint* sp = &seq[gg*64];
      while (__hip_atomic_load(sp, __ATOMIC_ACQUIRE, __HIP_MEMORY_SCOPE_AGENT) <= (uint)step) {}
      hq[wb][gg*36 + idx] = hglob[rb*128 + gg*32 + idx];
    }
    __syncthreads();
  }
}

__global__ void k_head1(const ushort* __restrict__ h, const float* __restrict__ w,
                        const float* __restrict__ b, float* __restrict__ out){
  __shared__ float s[256];
  int t = blockIdx.x, j = threadIdx.x;       // 128 threads
  s[j]       = bf2f(h[t*256 + j]);
  s[j + 128] = bf2f(h[t*256 + 128 + j]);
  __syncthreads();
  float acc = b[j];
  const float4* wr4 = (const float4*)(w + j*256);
  #pragma unroll
  for (int k4 = 0; k4 < 64; k4++){
    float4 v = wr4[k4];
    int k = k4*4;
    acc += s[k+0]*v.x + s[k+1]*v.y + s[k+2]*v.z + s[k+3]*v.w;
  }
  out[t*128 + j] = fmaxf(acc, 0.f);
}
__global__ void k_head2(const float* __restrict__ hm, const float* __restrict__ w,
                        const float* __restrict__ b, float* __restrict__ out){
  int t = blockIdx.x*256 + threadIdx.x;
  if (t < BSZ){
    float acc = b[0];
    #pragma unroll
    for (int k = 0; k < 128; k++) acc += hm[t*128 + k]*w[k];
    out[t] = acc;
  }
}

extern "C" void kernel_launch(void* const* d_in, const int* in_sizes, int n_in,
                              void* d_out, int out_size, void* d_ws, size_t ws_size,
                              hipStream_t stream){
  const float* x     = (const float*)d_in[0];
  const int*   ei    = (const int*)d_in[1];
  const int*   et    = (const int*)d_in[2];
  const int*   uidx  = (const int*)d_in[3];
  const int*   vidx  = (const int*)d_in[4];
  const float* basis = (const float*)d_in[5];
  const float* comp  = (const float*)d_in[6];
  const float* root  = (const float*)d_in[7];
  const float* cbias = (const float*)d_in[8];
  const float* w_ih  = (const float*)d_in[9];
  const float* w_hh  = (const float*)d_in[10];
  const float* b_ih  = (const float*)d_in[11];
  const float* b_hh  = (const float*)d_in[12];
  const float* lin1w = (const float*)d_in[13];
  const float* lin1b = (const float*)d_in[14];
  const float* lin2w = (const float*)d_in[15];
  const float* lin2b = (const float*)d_in[16];

  char* ws = (char*)d_ws;
  __half* whh16  = (__half*)(ws + 0);                 // 1 MB
  ushort* wihbf  = (ushort*)(ws + 1048576);           // 1 MB
  float*  inv    = (float*) (ws + 2097152);           // 2.5 MB
  ushort* states = (ushort*)(ws + 4718592);           // 32 MB
  char*   scr    = ws + 38273024;                     // scratch union
  uint2*  hb     = (uint2*)(scr);                     // GNN: 32 MB
  float*  agg    = (float*)(scr + 33554432);          // GNN: 16 MB
  ushort* z      = (ushort*)(scr + 0);                // LSTM phase aliases
  ushort* out1   = (ushort*)(scr + 2097152);
  ushort* out2   = (ushort*)(scr + 4194304);
  float*  hmid   = (float*) (scr + 6291456);
  float*  xg     = (float*) (scr + 8388608);          // 16 MB, ends scr+25165824
  uint*   seq    = (uint*)  (scr + 25165824);         // 1 KB (4 words, 256B apart)
  uint*   hglob  = (uint*)  (scr + 25166848);         // 1 KB (2 x 256 fp16)

  k_cvt_half<<<2048, 256, 0, stream>>>(w_hh, whh16, 2*1024*256);
  k_cvt_bf  <<<2048, 256, 0, stream>>>(w_ih, wihbf, 2*1024*256);
  hipMemsetAsync(inv, 0, (size_t)N_NODES*NREL*4, stream);
  k_count<<<N_EDGES/256, 256, 0, stream>>>(ei, et, (int*)inv);
  k_inv<<<(N_NODES*NREL)/256, 256, 0, stream>>>(inv);

  for (int l = 0; l < 4; l++){
    k_hb<<<N_NODES/8, 256, 0, stream>>>(x, states, l, basis + l*NBASIS*1024, hb);
    hipMemsetAsync(agg, 0, (size_t)N_NODES*32*4, stream);
    k_edge<<<N_EDGES/8, 256, 0, stream>>>(ei, et, comp + l*NREL*NBASIS, inv, hb, agg);
    k_combine<<<N_NODES/8, 256, 0, stream>>>(agg, x, states, l, root + l*1024, cbias + l*32);
  }

  k_gather<<<BSZ, 256, 0, stream>>>(states, uidx, vidx, z);
  k_xgemm<<<4096, 256, 0, stream>>>(z,    wihbf,          b_ih,        b_hh,        xg);
  hipMemsetAsync(seq, 0, 1024, stream);
  k_scan4<<<25, 256, 0, stream>>>(xg, whh16,          out1, seq, hglob);
  k_xgemm<<<4096, 256, 0, stream>>>(out1, wihbf + 262144, b_ih + 1024, b_hh + 1024, xg);
  hipMemsetAsync(seq, 0, 1024, stream);
  k_scan4<<<25, 256, 0, stream>>>(xg, whh16 + 262144, out2, seq, hglob);
  k_head1<<<BSZ, 128, 0, stream>>>(out2, lin1w, lin1b, hmid);
  k_head2<<<BSZ/256, 256, 0, stream>>>(hmid, lin2w, lin2b, (float*)d_out);
}

// Round 5
// 11071.671 us; speedup vs baseline: 1.9657x; 1.7871x over previous
//
#include <hip/hip_runtime.h>
#include <hip/hip_bf16.h>
#include <hip/hip_fp16.h>

#define N_NODES 131072
#define N_EDGES 2097152
#define BSZ     4096
#define NREL    5
#define NBASIS  4

typedef unsigned int uint;
typedef unsigned short ushort;
typedef _Float16 v2h __attribute__((ext_vector_type(2)));
typedef __attribute__((ext_vector_type(8))) short bf16x8;
typedef __attribute__((ext_vector_type(4))) float f32x4;
typedef uint u32x4v __attribute__((ext_vector_type(4)));

__device__ __forceinline__ float bflo(uint u){ union{uint i;float f;}x; x.i = u<<16; return x.f; }
__device__ __forceinline__ float bf2f(ushort u){ return bflo((uint)u); }
__device__ __forceinline__ ushort f2bf(float f){
  union{float f;uint i;}x; x.f=f;
  uint r = (x.i + 0x7fffu + ((x.i>>16)&1u)) >> 16;
  return (ushort)r;
}
__device__ __forceinline__ float sigm(float x){ return 1.0f/(1.0f+__expf(-x)); }
__device__ __forceinline__ float tanh_fast(float x){
  x = fminf(fmaxf(x,-15.f),15.f);
  float e = __expf(2.0f*x);
  return (e-1.0f)/(e+1.0f);
}
__device__ __forceinline__ float dot2h(uint a, uint b, float c){
#if __has_builtin(__builtin_amdgcn_fdot2)
  return __builtin_amdgcn_fdot2(__builtin_bit_cast(v2h,a), __builtin_bit_cast(v2h,b), c, false);
#else
  v2h ah = __builtin_bit_cast(v2h,a), bh = __builtin_bit_cast(v2h,b);
  return c + (float)ah.x*(float)bh.x + (float)ah.y*(float)bh.y;
#endif
}

// 16B single-copy-atomic exchange ops, device(L3)-coherent (sc0 sc1) so they are
// correct for ANY workgroup->XCD placement (per-XCD L2s are not cross-coherent).
__device__ __forceinline__ void store16(uint* p, u32x4v v){
  asm volatile("global_store_dwordx4 %0, %1, off sc0 sc1" :: "v"(p), "v"(v) : "memory");
}
__device__ __forceinline__ u32x4v poll16(const uint* p, uint want){
  u32x4v v;
  do {
    asm volatile("global_load_dwordx4 %0, %1, off sc0 sc1\n\ts_waitcnt vmcnt(0)"
      : "=v"(v) : "v"(p) : "memory");
  } while (v.x != want);
  return v;
}

__global__ void k_cvt_half(const float* __restrict__ in, __half* __restrict__ out, int n){
  int i = blockIdx.x*256 + threadIdx.x;
  if (i < n) out[i] = __float2half(in[i]);
}
__global__ void k_cvt_bf(const float* __restrict__ in, ushort* __restrict__ out, int n){
  int i = blockIdx.x*256 + threadIdx.x;
  if (i < n) out[i] = f2bf(in[i]);
}

__global__ void k_count(const int* __restrict__ ei, const int* __restrict__ et, int* __restrict__ cnt){
  int e = blockIdx.x*256 + threadIdx.x;
  if (e < N_EDGES){
    int d = ei[N_EDGES + e];
    int r = et[e];
    atomicAdd(&cnt[d*NREL + r], 1);
  }
}
__global__ void k_inv(float* __restrict__ buf){
  int i = blockIdx.x*256 + threadIdx.x;
  if (i < N_NODES*NREL){
    int c = ((int*)buf)[i];
    buf[i] = (c > 0) ? (1.0f/(float)c) : 1.0f;
  }
}

// hb[n][j][b] = sum_i h[n,i]*basis[b,i,j], packed 4 bf16 per (n,j)
__global__ void k_hb(const float* __restrict__ x, const ushort* __restrict__ states, int l,
                     const float* __restrict__ basis_l, uint2* __restrict__ hb){
  __shared__ float bs[NBASIS*32*32];
  __shared__ float hs[256];
  int tid = threadIdx.x;
  #pragma unroll
  for (int r = 0; r < 16; r++){ int idx = r*256 + tid; bs[idx] = basis_l[idx]; }
  int nbase = blockIdx.x*8;
  if (l == 0){
    hs[tid] = x[nbase*32 + tid];
  } else {
    int n = nbase + (tid >> 5), i = tid & 31;
    hs[tid] = bf2f(states[n*128 + (l-1)*32 + i]);
  }
  __syncthreads();
  int nl = tid >> 5, j = tid & 31;
  float a0=0.f,a1=0.f,a2=0.f,a3=0.f;
  #pragma unroll
  for (int i = 0; i < 32; i++){
    float hv = hs[nl*32 + i];
    a0 += hv*bs[0*1024 + i*32 + j];
    a1 += hv*bs[1*1024 + i*32 + j];
    a2 += hv*bs[2*1024 + i*32 + j];
    a3 += hv*bs[3*1024 + i*32 + j];
  }
  uint2 o;
  o.x = (uint)f2bf(a0) | ((uint)f2bf(a1) << 16);
  o.y = (uint)f2bf(a2) | ((uint)f2bf(a3) << 16);
  hb[(nbase + nl)*32 + j] = o;
}

__global__ void k_edge(const int* __restrict__ ei, const int* __restrict__ et,
                       const float* __restrict__ comp_l, const float* __restrict__ inv,
                       const uint2* __restrict__ hb, float* __restrict__ agg){
  __shared__ float cl[NREL*NBASIS];
  int tid = threadIdx.x;
  if (tid < NREL*NBASIS) cl[tid] = comp_l[tid];
  __syncthreads();
  int e = blockIdx.x*8 + (tid >> 5);
  int j = tid & 31;
  int src = ei[e];
  int dst = ei[N_EDGES + e];
  int r = et[e];
  float nrm = inv[dst*NREL + r];
  uint2 v = hb[src*32 + j];
  float m = nrm*(cl[r*4+0]*bflo(v.x)       + cl[r*4+1]*bflo(v.x >> 16)
               + cl[r*4+2]*bflo(v.y)       + cl[r*4+3]*bflo(v.y >> 16));
  atomicAdd(&agg[dst*32 + j], m);
}

__global__ void k_combine(const float* __restrict__ agg, const float* __restrict__ x,
                          ushort* __restrict__ states, int l,
                          const float* __restrict__ root_l, const float* __restrict__ bias_l){
  __shared__ float rt[1024];
  __shared__ float hs[256];
  int tid = threadIdx.x;
  #pragma unroll
  for (int r = 0; r < 4; r++) rt[r*256 + tid] = root_l[r*256 + tid];
  int nbase = blockIdx.x*8;
  if (l == 0){
    hs[tid] = x[nbase*32 + tid];
  } else {
    int n = nbase + (tid >> 5), i = tid & 31;
    hs[tid] = bf2f(states[n*128 + (l-1)*32 + i]);
  }
  __syncthreads();
  int nl = tid >> 5, j = tid & 31;
  int n = nbase + nl;
  float acc = agg[n*32 + j] + bias_l[j];
  #pragma unroll
  for (int i = 0; i < 32; i++) acc += hs[nl*32 + i] * rt[i*32 + j];
  states[n*128 + l*32 + j] = f2bf(tanh_fast(acc));
}

__global__ void k_gather(const ushort* __restrict__ states, const int* __restrict__ uidx,
                         const int* __restrict__ vidx, ushort* __restrict__ z){
  int b = blockIdx.x;
  int k = threadIdx.x;                       // 256
  int node = (k < 128) ? uidx[b] : vidx[b];
  z[b*256 + k] = states[node*128 + (k & 127)];
}

__global__ void k_xgemm(const ushort* __restrict__ A, const ushort* __restrict__ W,
                        const float* __restrict__ bih, const float* __restrict__ bhh,
                        float* __restrict__ xg){
  int gw = blockIdx.x*4 + (threadIdx.x >> 6);
  int lane = threadIdx.x & 63;
  int t0 = (gw >> 6)*16;
  int j0 = (gw & 63)*16;
  int m = lane & 15, q = lane >> 4;
  const ushort* ap = A + (t0 + m)*256 + q*8;
  const ushort* bp = W + (j0 + m)*256 + q*8;
  f32x4 acc = {0.f,0.f,0.f,0.f};
  #pragma unroll
  for (int kk = 0; kk < 8; kk++){
    bf16x8 a = *(const bf16x8*)(ap + kk*32);
    bf16x8 b = *(const bf16x8*)(bp + kk*32);
    acc = __builtin_amdgcn_mfma_f32_16x16x32_bf16(a, b, acc, 0, 0, 0);
  }
  int j = j0 + m;
  float bias = bih[j] + bhh[j];
  #pragma unroll
  for (int r = 0; r < 4; r++){
    int t = t0 + q*4 + r;                    // C: col=lane&15, row=quad*4+reg (m89)
    xg[t*1024 + j] = acc[r] + bias;
  }
}

// ---- 4-WG cooperative LSTM scan, quad-split dot + DPP reduce ----
// WG g owns units [g*64,(g+1)*64). Thread: wave w, quad qd, sub s. Unit u =
// g*64+w*16+qd; thread computes k-quarter [64s,64s+64) of the 4 gate rows of u;
// quad DPP butterflies give every lane the full gate sums -> every lane has hv.
// Cross-WG exchange: self-validating 16B chunks {tag, 4x fp16 h} assembled
// in-register via ds_bpermute, stored/polled with sc0 sc1 (L3-coherent, single
// round trip, no fences, no L1 invalidates). One __syncthreads per step.
#define REP8J(M,q) M(q,0) M(q,1) M(q,2) M(q,3) M(q,4) M(q,5) M(q,6) M(q,7)
#define REPQ(M) REP8J(M,0) REP8J(M,1) REP8J(M,2) REP8J(M,3)
#define WDECL(q,j) uint4 W##q##_##j = wp##q[j];
#define WPIN(q,j)  asm volatile("" : "+v"(W##q##_##j.x), "+v"(W##q##_##j.y), \
                                     "+v"(W##q##_##j.z), "+v"(W##q##_##j.w));
#define DOTJ(j) { uint4 H = hp[j]; \
  a0 = dot2h(W0_##j.x, H.x, a0); b0 = dot2h(W0_##j.y, H.y, b0); \
  a0 = dot2h(W0_##j.z, H.z, a0); b0 = dot2h(W0_##j.w, H.w, b0); \
  a1 = dot2h(W1_##j.x, H.x, a1); b1 = dot2h(W1_##j.y, H.y, b1); \
  a1 = dot2h(W1_##j.z, H.z, a1); b1 = dot2h(W1_##j.w, H.w, b1); \
  a2 = dot2h(W2_##j.x, H.x, a2); b2 = dot2h(W2_##j.y, H.y, b2); \
  a2 = dot2h(W2_##j.z, H.z, a2); b2 = dot2h(W2_##j.w, H.w, b2); \
  a3 = dot2h(W3_##j.x, H.x, a3); b3 = dot2h(W3_##j.y, H.y, b3); \
  a3 = dot2h(W3_##j.z, H.z, a3); b3 = dot2h(W3_##j.w, H.w, b3); }
#define BFLY(r) { \
  float _t = __int_as_float(__builtin_amdgcn_update_dpp(0, __float_as_int(r), 0xB1, 0xF, 0xF, true)); \
  r += _t; \
  _t = __int_as_float(__builtin_amdgcn_update_dpp(0, __float_as_int(r), 0x4E, 0xF, 0xF, true)); \
  r += _t; }

__launch_bounds__(256, 1)
__global__ void k_scan4(const float* __restrict__ xg, const __half* __restrict__ whh,
                        ushort* __restrict__ outh, uint* hx){
  int b = blockIdx.x;
  if (b & 7) return;
  int g = b >> 3;
  if (g >= 4) return;
  __shared__ uint hq[2][144];                // 2 bufs x 4 quarters x 36 uints (pad)
  int t = threadIdx.x;
  int w = t >> 6, lane = t & 63, qd = lane >> 2, s = lane & 3;
  int u = g*64 + w*16 + qd;
  const uint4* wp0 = (const uint4*)(whh + ((size_t)(u      ))*256 + s*64);
  const uint4* wp1 = (const uint4*)(whh + ((size_t)(u + 256))*256 + s*64);
  const uint4* wp2 = (const uint4*)(whh + ((size_t)(u + 512))*256 + s*64);
  const uint4* wp3 = (const uint4*)(whh + ((size_t)(u + 768))*256 + s*64);
  REPQ(WDECL)
  REPQ(WPIN)
  if (t < 144) hq[0][t] = 0u;
  float c = 0.f;
  float px = xg[s*256 + u];
  int pollidx = t - 64;                      // threads 64..111 poll remote chunks
  int bb = (lane & 48) * 4;                  // bpermute byte base: lane16-group
  __syncthreads();
  for (int step = 0; step < 4096; step++){
    int rb = step & 1, wb = rb ^ 1;
    const uint4* hp = (const uint4*)&hq[rb][s*36];
    float a0=0.f,a1=0.f,a2=0.f,a3=0.f,b0=0.f,b1=0.f,b2=0.f,b3=0.f;
    int nstep = (step < 4095) ? step + 1 : step;
    float npx = xg[(size_t)nstep*1024 + s*256 + u];
    DOTJ(0) DOTJ(1) DOTJ(2) DOTJ(3) DOTJ(4) DOTJ(5) DOTJ(6) DOTJ(7)
    float r0 = a0 + b0, r1 = a1 + b1, r2 = a2 + b2, r3 = a3 + b3;
    r0 += (s == 0) ? px : 0.f;
    r1 += (s == 1) ? px : 0.f;
    r2 += (s == 2) ? px : 0.f;
    r3 += (s == 3) ? px : 0.f;
    BFLY(r0) BFLY(r1) BFLY(r2) BFLY(r3)
    float iv = sigm(r0), fv = sigm(r1), gv = tanh_fast(r2), ov = sigm(r3);
    c = fv*c + iv*gv;
    float hv = ov*tanh_fast(c);
    px = npx;
    // assemble 4-unit chunks in-register: gather quad values within the wave
    uint hvh = (uint)__half_as_ushort(__float2half(hv));
    uint g0 = (uint)__builtin_amdgcn_ds_bpermute(bb +  0, (int)hvh);
    uint g1 = (uint)__builtin_amdgcn_ds_bpermute(bb + 16, (int)hvh);
    uint g2 = (uint)__builtin_amdgcn_ds_bpermute(bb + 32, (int)hvh);
    uint g3 = (uint)__builtin_amdgcn_ds_bpermute(bb + 48, (int)hvh);
    if ((lane & 15) == 0){                   // 4 builder lanes per wave
      int cc = w*4 + (lane >> 4);            // chunk 0..15, units 4cc..4cc+3
      u32x4v ch;
      ch.x = (uint)(step + 1);
      ch.y = (g0 & 0xffffu) | (g1 << 16);
      ch.z = (g2 & 0xffffu) | (g3 << 16);
      ch.w = 0u;
      store16(hx + (((size_t)rb*4 + g)*16 + cc)*4, ch);
    }
    if (s == 0){                             // own quarter into LDS + bf16 output
      ((__half*)&hq[wb][g*36])[w*16 + qd] = __ushort_as_half((ushort)hvh);
      outh[(size_t)step*256 + u] = f2bf(hv);
    }
    if ((uint)pollidx < 48u){                // 3 remote WGs x 16 chunks
      int o = pollidx >> 4, cc = pollidx & 15;
      int gg = o + (o >= g);
      u32x4v v = poll16(hx + (((size_t)rb*4 + gg)*16 + cc)*4, (uint)(step + 1));
      hq[wb][gg*36 + 2*cc]     = v.y;
      hq[wb][gg*36 + 2*cc + 1] = v.z;
    }
    __syncthreads();
  }
}

__global__ void k_head1(const ushort* __restrict__ h, const float* __restrict__ w,
                        const float* __restrict__ b, float* __restrict__ out){
  __shared__ float s[256];
  int t = blockIdx.x, j = threadIdx.x;       // 128 threads
  s[j]       = bf2f(h[t*256 + j]);
  s[j + 128] = bf2f(h[t*256 + 128 + j]);
  __syncthreads();
  float acc = b[j];
  const float4* wr4 = (const float4*)(w + j*256);
  #pragma unroll
  for (int k4 = 0; k4 < 64; k4++){
    float4 v = wr4[k4];
    int k = k4*4;
    acc += s[k+0]*v.x + s[k+1]*v.y + s[k+2]*v.z + s[k+3]*v.w;
  }
  out[t*128 + j] = fmaxf(acc, 0.f);
}
__global__ void k_head2(const float* __restrict__ hm, const float* __restrict__ w,
                        const float* __restrict__ b, float* __restrict__ out){
  int t = blockIdx.x*256 + threadIdx.x;
  if (t < BSZ){
    float acc = b[0];
    #pragma unroll
    for (int k = 0; k < 128; k++) acc += hm[t*128 + k]*w[k];
    out[t] = acc;
  }
}

extern "C" void kernel_launch(void* const* d_in, const int* in_sizes, int n_in,
                              void* d_out, int out_size, void* d_ws, size_t ws_size,
                              hipStream_t stream){
  const float* x     = (const float*)d_in[0];
  const int*   ei    = (const int*)d_in[1];
  const int*   et    = (const int*)d_in[2];
  const int*   uidx  = (const int*)d_in[3];
  const int*   vidx  = (const int*)d_in[4];
  const float* basis = (const float*)d_in[5];
  const float* comp  = (const float*)d_in[6];
  const float* root  = (const float*)d_in[7];
  const float* cbias = (const float*)d_in[8];
  const float* w_ih  = (const float*)d_in[9];
  const float* w_hh  = (const float*)d_in[10];
  const float* b_ih  = (const float*)d_in[11];
  const float* b_hh  = (const float*)d_in[12];
  const float* lin1w = (const float*)d_in[13];
  const float* lin1b = (const float*)d_in[14];
  const float* lin2w = (const float*)d_in[15];
  const float* lin2b = (const float*)d_in[16];

  char* ws = (char*)d_ws;
  __half* whh16  = (__half*)(ws + 0);                 // 1 MB
  ushort* wihbf  = (ushort*)(ws + 1048576);           // 1 MB
  float*  inv    = (float*) (ws + 2097152);           // 2.5 MB
  ushort* states = (ushort*)(ws + 4718592);           // 32 MB
  char*   scr    = ws + 38273024;                     // scratch union
  uint2*  hb     = (uint2*)(scr);                     // GNN: 32 MB
  float*  agg    = (float*)(scr + 33554432);          // GNN: 16 MB
  ushort* z      = (ushort*)(scr + 0);                // LSTM phase aliases
  ushort* out1   = (ushort*)(scr + 2097152);
  ushort* out2   = (ushort*)(scr + 4194304);
  float*  hmid   = (float*) (scr + 6291456);
  float*  xg     = (float*) (scr + 8388608);          // 16 MB, ends scr+25165824
  uint*   hx1    = (uint*)  (scr + 25165824);         // 2 KB chunk exchange, scan 1
  uint*   hx2    = (uint*)  (scr + 25167872);         // 2 KB chunk exchange, scan 2

  k_cvt_half<<<2048, 256, 0, stream>>>(w_hh, whh16, 2*1024*256);
  k_cvt_bf  <<<2048, 256, 0, stream>>>(w_ih, wihbf, 2*1024*256);
  hipMemsetAsync(inv, 0, (size_t)N_NODES*NREL*4, stream);
  k_count<<<N_EDGES/256, 256, 0, stream>>>(ei, et, (int*)inv);
  k_inv<<<(N_NODES*NREL)/256, 256, 0, stream>>>(inv);

  for (int l = 0; l < 4; l++){
    k_hb<<<N_NODES/8, 256, 0, stream>>>(x, states, l, basis + l*NBASIS*1024, hb);
    hipMemsetAsync(agg, 0, (size_t)N_NODES*32*4, stream);
    k_edge<<<N_EDGES/8, 256, 0, stream>>>(ei, et, comp + l*NREL*NBASIS, inv, hb, agg);
    k_combine<<<N_NODES/8, 256, 0, stream>>>(agg, x, states, l, root + l*1024, cbias + l*32);
  }

  k_gather<<<BSZ, 256, 0, stream>>>(states, uidx, vidx, z);
  k_xgemm<<<4096, 256, 0, stream>>>(z,    wihbf,          b_ih,        b_hh,        xg);
  k_scan4<<<25, 256, 0, stream>>>(xg, whh16,          out1, hx1);
  k_xgemm<<<4096, 256, 0, stream>>>(out1, wihbf + 262144, b_ih + 1024, b_hh + 1024, xg);
  k_scan4<<<25, 256, 0, stream>>>(xg, whh16 + 262144, out2, hx2);
  k_head1<<<BSZ, 128, 0, stream>>>(out2, lin1w, lin1b, hmid);
  k_head2<<<BSZ/256, 256, 0, stream>>>(hmid, lin2w, lin2b, (float*)d_out);
}